// Round 1
// baseline (23.786 us; speedup 1.0000x reference)
//
#include <hip/hip_runtime.h>

#define DD 6
#define CAPF 20.0f
#define BIGF 1e30f

__global__ __launch_bounds__(256) void proj_wl1_kernel(
    const float* __restrict__ x, const float* __restrict__ s,
    float* __restrict__ out, int B)
{
    int b = blockIdx.x * blockDim.x + threadIdx.x;
    if (b >= B) return;

    // ---- load q (row of x): 24B per row, 8B-aligned -> 3x float2 ----
    const float* xp = x + (size_t)b * DD;
    float2 q01 = *reinterpret_cast<const float2*>(xp + 0);
    float2 q23 = *reinterpret_cast<const float2*>(xp + 2);
    float2 q45 = *reinterpret_cast<const float2*>(xp + 4);
    float q[DD] = {q01.x, q01.y, q23.x, q23.y, q45.x, q45.y};

    // ---- load weights w = |s[:,11:17]| (stride-17 rows, 4B aligned -> scalar) ----
    const float* sp = s + (size_t)b * 17 + 11;
    float w[DD];
#pragma unroll
    for (int i = 0; i < DD; ++i) w[i] = fabsf(sp[i]);

    // ---- per-coordinate precompute ----
    float a[DD], r[DD], wq[DD], w2[DD];
    float total = 0.f;
#pragma unroll
    for (int i = 0; i < DD; ++i) {
        a[i]  = fabsf(q[i]);
        wq[i] = w[i] * a[i];
        w2[i] = w[i] * w[i];
        total += wq[i];
        r[i]  = (w[i] > 0.f) ? (a[i] / w[i]) : BIGF;
    }

    // ---- sort (r, wq, w2) descending by r: unrolled bubble network (15 cswaps) ----
#pragma unroll
    for (int i = 0; i < DD - 1; ++i) {
#pragma unroll
        for (int j = 0; j < DD - 1 - i; ++j) {
            bool sw = r[j] < r[j + 1];
            float t0 = r[j],  t1 = wq[j], t2 = w2[j];
            r[j]  = sw ? r[j + 1]  : r[j];
            wq[j] = sw ? wq[j + 1] : wq[j];
            w2[j] = sw ? w2[j + 1] : w2[j];
            r[j + 1]  = sw ? t0 : r[j + 1];
            wq[j + 1] = sw ? t1 : wq[j + 1];
            w2[j + 1] = sw ? t2 : w2[j + 1];
        }
    }

    // ---- prefix sums, candidate lambdas, validity count (exact ref semantics) ----
    float cwq = 0.f, cw2 = 0.f;
    float lamk[DD];
    int m = 0;
#pragma unroll
    for (int k = 0; k < DD; ++k) {
        cwq += wq[k];
        cw2 += w2[k];
        float safe = (cw2 > 0.f) ? cw2 : 1.f;
        lamk[k] = (cwq - CAPF) / safe;
        bool valid = (r[k] > lamk[k]) && (cw2 > 0.f);
        m += valid ? 1 : 0;
    }
    int ks = m - 1;
    if (ks < 0) ks = 0;
    // compile-time-unrolled select chain (keeps lamk in registers, no scratch)
    float lam = lamk[0];
#pragma unroll
    for (int k = 1; k < DD; ++k) lam = (ks == k) ? lamk[k] : lam;
    lam = (total > CAPF) ? fmaxf(lam, 0.f) : 0.f;

    // ---- shrink and write ----
    float o[DD];
#pragma unroll
    for (int i = 0; i < DD; ++i) {
        float mag = fmaxf(a[i] - lam * w[i], 0.f);
        float sgn = (q[i] > 0.f) ? 1.f : ((q[i] < 0.f) ? -1.f : 0.f);
        o[i] = sgn * mag;
    }
    float* op = out + (size_t)b * DD;
    *reinterpret_cast<float2*>(op + 0) = make_float2(o[0], o[1]);
    *reinterpret_cast<float2*>(op + 2) = make_float2(o[2], o[3]);
    *reinterpret_cast<float2*>(op + 4) = make_float2(o[4], o[5]);
}

extern "C" void kernel_launch(void* const* d_in, const int* in_sizes, int n_in,
                              void* d_out, int out_size, void* d_ws, size_t ws_size,
                              hipStream_t stream)
{
    const float* x = (const float*)d_in[0];
    const float* s = (const float*)d_in[1];
    float* out = (float*)d_out;
    int B = in_sizes[0] / DD;

    const int block = 256;
    int grid = (B + block - 1) / block;
    proj_wl1_kernel<<<grid, block, 0, stream>>>(x, s, out, B);
}